// Round 6
// baseline (235.803 us; speedup 1.0000x reference)
//
#include <hip/hip_runtime.h>
#include <math.h>

#define NBINS 15
#define TROWS 64
#define NC 100
#define BLOCK 256

// gbins layout in d_ws: [0..14]=counts, [15..29]=sum_conf, [30..44]=sum_acc
__global__ __launch_bounds__(BLOCK, 4) void ece_main(const float* __restrict__ logits,
                                                     const int* __restrict__ labels,
                                                     const int* __restrict__ t_opt,
                                                     float* __restrict__ gbins,
                                                     int N) {
    __shared__ __align__(16) float s_tile[TROWS * NC];   // 25.6 KB, single buffer
    __shared__ float s_cnt[NBINS], s_conf[NBINS], s_acc[NBINS];

    const int tid = threadIdx.x;
    if (tid < NBINS) { s_cnt[tid] = 0.f; s_conf[tid] = 0.f; s_acc[tid] = 0.f; }

    const int r = tid >> 2;          // row in tile 0..63
    const int q = tid & 3;           // quarter of row

    const int tt = t_opt[0];
    const float scale = (tt != 0) ? (1.0f / (float)tt) : 1.0f;

    const int nTiles = (N + TROWS - 1) / TROWS;
    const int stride = gridDim.x;

    float4 sv[7];                    // staging registers (coalesced order)
    int    svn = 0;                  // valid float4 count this tile

    auto LOADREG = [&](int tile) {   // issue coalesced global loads -> regs
        const long long rbase = (long long)tile * TROWS;
        const int nf4 = min(TROWS, (int)(N - rbase)) * (NC / 4);
        const float4* __restrict__ src = (const float4*)(logits + rbase * NC);
        #pragma unroll
        for (int i = 0; i < 7; ++i) {
            const int k = tid + i * BLOCK;
            if (k < nf4) sv[i] = src[k];             // global_load_dwordx4, 1KB/wave-instr
        }
        svn = nf4;
    };

    int t = blockIdx.x;
    if (t < nTiles) LOADREG(t);

    for (; t < nTiles; t += stride) {
        __syncthreads();             // prev compute done reading s_tile; drains vmcnt -> sv ready

        #pragma unroll               // regs -> LDS, natural conflict-free b128 pattern
        for (int i = 0; i < 7; ++i) {
            const int k = tid + i * BLOCK;
            if (k < svn) ((float4*)s_tile)[k] = sv[i];
        }
        __syncthreads();             // writes visible

        const int nxt = t + stride;
        if (nxt < nTiles) LOADREG(nxt);   // in flight across compute + next barrier

        // ---- compute tile t: 4 threads/row ----
        const long long rbase = (long long)t * TROWS;
        if (rbase + r < N) {
            const float4* rowp = (const float4*)&s_tile[r * NC];
            const int nf = (q == 0) ? 7 : 6;
            const int fb = (q == 0) ? 0 : (1 + q * 6);   // f4 ranges: 0-6,7-12,13-18,19-24

            float4 v[7];
            #pragma unroll
            for (int j = 0; j < 7; ++j)
                if (j < nf) v[j] = rowp[fb + j];          // ds_read_b128, static idx

            float m = -INFINITY; int mi = 0;
            #pragma unroll
            for (int j = 0; j < 7; ++j) if (j < nf) {
                const int cb = (fb + j) * 4;
                float4 w = v[j];
                w.x *= scale; w.y *= scale; w.z *= scale; w.w *= scale;
                v[j] = w;
                if (w.x > m) { m = w.x; mi = cb;     }
                if (w.y > m) { m = w.y; mi = cb + 1; }
                if (w.z > m) { m = w.z; mi = cb + 2; }
                if (w.w > m) { m = w.w; mi = cb + 3; }
            }
            #pragma unroll
            for (int off = 1; off <= 2; off <<= 1) {
                const float om  = __shfl_xor(m, off);
                const int   omi = __shfl_xor(mi, off);
                if (om > m || (om == m && omi < mi)) { m = om; mi = omi; }
            }

            float e = 0.f;
            #pragma unroll
            for (int j = 0; j < 7; ++j) if (j < nf) {
                const float4 w = v[j];
                e += __expf(w.x - m) + __expf(w.y - m)
                   + __expf(w.z - m) + __expf(w.w - m);
            }
            e += __shfl_xor(e, 1);
            e += __shfl_xor(e, 2);

            if (q == 0) {
                const float conf = 1.0f / e;
                const float acc  = (mi == labels[rbase + r]) ? 1.0f : 0.0f;

                // searchsorted(linspace(0,1,16), conf, 'left') - 1, clipped
                int jc = 0;
                #pragma unroll
                for (int i = 0; i <= NBINS; ++i) {
                    const float b = (float)i * (1.0f / 15.0f);
                    jc += (b < conf) ? 1 : 0;
                }
                int bin = jc - 1;
                bin = bin < 0 ? 0 : (bin > NBINS - 1 ? NBINS - 1 : bin);

                atomicAdd(&s_cnt[bin],  1.0f);
                atomicAdd(&s_conf[bin], conf);
                atomicAdd(&s_acc[bin],  acc);
            }
        }
    }

    __syncthreads();                 // all histogram atomics done before flush
    if (tid < NBINS) {
        atomicAdd(&gbins[tid],             s_cnt[tid]);
        atomicAdd(&gbins[NBINS + tid],     s_conf[tid]);
        atomicAdd(&gbins[2 * NBINS + tid], s_acc[tid]);
    }
}

__global__ void ece_final(const float* __restrict__ gbins,
                          float* __restrict__ out, int N) {
    if (threadIdx.x == 0 && blockIdx.x == 0) {
        float ece = 0.f;
        for (int b = 0; b < NBINS; ++b) {
            const float c = gbins[b];
            if (c > 0.f) {
                const float avg_conf = gbins[NBINS + b] / c;
                const float avg_acc  = gbins[2 * NBINS + b] / c;
                ece += fabsf(avg_conf - avg_acc) * (c / (float)N);
            }
        }
        out[0] = ece;
    }
}

extern "C" void kernel_launch(void* const* d_in, const int* in_sizes, int n_in,
                              void* d_out, int out_size, void* d_ws, size_t ws_size,
                              hipStream_t stream) {
    const float* logits = (const float*)d_in[0];
    const int*   labels = (const int*)d_in[1];
    const int*   t_opt  = (const int*)d_in[2];
    float* out   = (float*)d_out;
    float* gbins = (float*)d_ws;

    const int N = in_sizes[1];               // 1,000,000 rows (C fixed at 100)

    hipMemsetAsync(gbins, 0, 3 * NBINS * sizeof(float), stream);

    const int nTiles = (N + TROWS - 1) / TROWS;
    const int blocks = nTiles < 1024 ? nTiles : 1024;   // 4 blocks/CU x 256 CU
    ece_main<<<blocks, BLOCK, 0, stream>>>(logits, labels, t_opt, gbins, N);
    ece_final<<<1, 64, 0, stream>>>(gbins, out, N);
}

// Round 7
// 95.281 us; speedup vs baseline: 2.4748x; 2.4748x over previous
//
#include <hip/hip_runtime.h>
#include <math.h>

#define NBINS 15
#define TROWS 64
#define NC 100
#define F4_PER_ROW 25
#define F4_PER_TILE (TROWS * F4_PER_ROW)   // 1600
#define BLOCK 256

__device__ __forceinline__ void compute_tile(
    const float4* __restrict__ buf, int r, int q, long long rbase, int labCur,
    float scale, int N, float* s_cnt, float* s_conf, float* s_acc)
{
    if (rbase + r >= N) return;
    const float4* rowp = buf + r * F4_PER_ROW;
    const int nf = (q == 0) ? 7 : 6;
    const int fb = (q == 0) ? 0 : (1 + q * 6);   // f4 ranges: 0-6,7-12,13-18,19-24

    float4 v[7];
#pragma unroll
    for (int j = 0; j < 7; ++j)
        if (j < nf) v[j] = rowp[fb + j];          // ds_read_b128, static idx

    float m = -INFINITY; int mi = 0;
#pragma unroll
    for (int j = 0; j < 7; ++j) if (j < nf) {
        const int cb = (fb + j) * 4;
        float4 w = v[j];
        w.x *= scale; w.y *= scale; w.z *= scale; w.w *= scale;
        v[j] = w;
        if (w.x > m) { m = w.x; mi = cb;     }
        if (w.y > m) { m = w.y; mi = cb + 1; }
        if (w.z > m) { m = w.z; mi = cb + 2; }
        if (w.w > m) { m = w.w; mi = cb + 3; }
    }
#pragma unroll
    for (int off = 1; off <= 2; off <<= 1) {
        const float om  = __shfl_xor(m, off);
        const int   omi = __shfl_xor(mi, off);
        if (om > m || (om == m && omi < mi)) { m = om; mi = omi; }
    }

    float e = 0.f;
#pragma unroll
    for (int j = 0; j < 7; ++j) if (j < nf) {
        const float4 w = v[j];
        e += __expf(w.x - m) + __expf(w.y - m)
           + __expf(w.z - m) + __expf(w.w - m);
    }
    e += __shfl_xor(e, 1);
    e += __shfl_xor(e, 2);

    if (q == 0) {
        const float conf = 1.0f / e;
        const float acc  = (mi == labCur) ? 1.0f : 0.0f;
        int jc = 0;
#pragma unroll
        for (int i = 0; i <= NBINS; ++i) {
            const float b = (float)i * (1.0f / 15.0f);
            jc += (b < conf) ? 1 : 0;
        }
        int bin = jc - 1;
        bin = bin < 0 ? 0 : (bin > NBINS - 1 ? NBINS - 1 : bin);
        atomicAdd(&s_cnt[bin],  1.0f);
        atomicAdd(&s_conf[bin], conf);
        atomicAdd(&s_acc[bin],  acc);
    }
}

// gbins layout in d_ws: [0..14]=counts, [15..29]=sum_conf, [30..44]=sum_acc
__global__ __launch_bounds__(BLOCK, 3) void ece_main(const float* __restrict__ logits,
                                                     const int* __restrict__ labels,
                                                     const int* __restrict__ t_opt,
                                                     float* __restrict__ gbins,
                                                     int N) {
    __shared__ float4 s_tile[2][F4_PER_TILE];        // 2 x 25.6 KB
    __shared__ float s_cnt[NBINS], s_conf[NBINS], s_acc[NBINS];

    const int tid = threadIdx.x;
    if (tid < NBINS) { s_cnt[tid] = 0.f; s_conf[tid] = 0.f; s_acc[tid] = 0.f; }

    const int lane   = tid & 63;
    const int wv     = tid >> 6;
    const int wvBase = wv * 400;       // f4 slots per wave per tile
    const int r      = tid >> 2;       // row in tile 0..63
    const int q      = tid & 3;        // quarter of row

    const int tt = t_opt[0];
    float scale = (tt != 0) ? (1.0f / (float)tt) : 1.0f;
    asm volatile("" :: "v"(scale));    // drain t_opt load before staging begins

    const float4* __restrict__ lg4 = (const float4*)logits;
    const long long lim = (long long)N * F4_PER_ROW - 1;
    const int nTiles = (N + TROWS - 1) / TROWS;
    const int stride = gridDim.x;

    // named staging registers (NO arrays/lambdas -> no scratch demotion)
    float4 sA0, sA1, sA2, sA3, sA4, sA5, sA6;  int labsA = 0;
    float4 sB0, sB1, sB2, sB3, sB4, sB5, sB6;  int labsB = 0;

#define CLK(kk) ((kk) < lim ? (kk) : lim)
#define ISSUE(P, tile) do {                                                   \
    const long long tb_ = (long long)(tile) * F4_PER_TILE + wvBase + lane;    \
    P##0 = lg4[CLK(tb_)];                                                     \
    P##1 = lg4[CLK(tb_ + 64)];                                                \
    P##2 = lg4[CLK(tb_ + 128)];                                               \
    P##3 = lg4[CLK(tb_ + 192)];                                               \
    P##4 = lg4[CLK(tb_ + 256)];                                               \
    P##5 = lg4[CLK(tb_ + 320)];                                               \
    if (lane < 16) P##6 = lg4[CLK(tb_ + 384)];                                \
    if (q == 0) {                                                             \
        long long rr_ = (long long)(tile) * TROWS + (tid >> 2);               \
        lab##P = labels[rr_ < N ? rr_ : (N - 1)];                             \
    }                                                                          \
} while (0)
// each ISSUE = exactly 8 vmem loads per wave (6 full + 2 exec-masked)

#define DSW(P, b) do {                                                        \
    float4* d_ = &s_tile[b][wvBase + lane];                                   \
    d_[0]   = P##0; d_[64]  = P##1; d_[128] = P##2;                           \
    d_[192] = P##3; d_[256] = P##4; d_[320] = P##5;                           \
    if (lane < 16) d_[384] = P##6;                                            \
} while (0)

#define VMW8  asm volatile("s_waitcnt vmcnt(8)" ::: "memory")
#define VMW0  asm volatile("s_waitcnt vmcnt(0)" ::: "memory")
#define LGKM0 asm volatile("s_waitcnt lgkmcnt(0)" ::: "memory")
#define SB    __builtin_amdgcn_sched_barrier(0)
#define BAR   __builtin_amdgcn_s_barrier()

    int  t     = blockIdx.x;
    bool vCur  = (t < nTiles);
    bool vNext = (t + stride < nTiles);
    int  cur   = 0;

    if (vCur)  ISSUE(sA, t);
    if (vNext) ISSUE(sB, t + stride);
    if (vCur) {
        if (vNext) VMW8; else VMW0;    // set A landed; B stays in flight
        SB;
        DSW(sA, 0);
    }
    LGKM0; SB; BAR; SB;

    if (vCur) for (;;) {
        {   // phase A: buf[cur]=tile t (from set A); set B = t+stride in flight
            const int  tn2 = t + 2 * stride;
            const bool v2  = tn2 < nTiles;
            const int  labCur = labsA;            // copy before re-issue clobbers
            if (v2) ISSUE(sA, tn2);
            compute_tile(s_tile[cur], r, q, (long long)t * TROWS, labCur,
                         scale, N, s_cnt, s_conf, s_acc);
            if (vNext) {
                if (v2) VMW8; else VMW0;          // set B landed
                SB;
                DSW(sB, cur ^ 1);
            }
            LGKM0; SB; BAR; SB;
            vCur = vNext; vNext = v2; t += stride; cur ^= 1;
            if (!vCur) break;
        }
        {   // phase B: roles swapped
            const int  tn2 = t + 2 * stride;
            const bool v2  = tn2 < nTiles;
            const int  labCur = labsB;
            if (v2) ISSUE(sB, tn2);
            compute_tile(s_tile[cur], r, q, (long long)t * TROWS, labCur,
                         scale, N, s_cnt, s_conf, s_acc);
            if (vNext) {
                if (v2) VMW8; else VMW0;          // set A landed
                SB;
                DSW(sA, cur ^ 1);
            }
            LGKM0; SB; BAR; SB;
            vCur = vNext; vNext = v2; t += stride; cur ^= 1;
            if (!vCur) break;
        }
    }

    VMW0;                 // safety: no loads left at endpgm
    __syncthreads();      // all histogram atomics done before flush
    if (tid < NBINS) {
        atomicAdd(&gbins[tid],             s_cnt[tid]);
        atomicAdd(&gbins[NBINS + tid],     s_conf[tid]);
        atomicAdd(&gbins[2 * NBINS + tid], s_acc[tid]);
    }
#undef CLK
#undef ISSUE
#undef DSW
#undef VMW8
#undef VMW0
#undef LGKM0
#undef SB
#undef BAR
}

__global__ void ece_final(const float* __restrict__ gbins,
                          float* __restrict__ out, int N) {
    if (threadIdx.x == 0 && blockIdx.x == 0) {
        float ece = 0.f;
        for (int b = 0; b < NBINS; ++b) {
            const float c = gbins[b];
            if (c > 0.f) {
                const float avg_conf = gbins[NBINS + b] / c;
                const float avg_acc  = gbins[2 * NBINS + b] / c;
                ece += fabsf(avg_conf - avg_acc) * (c / (float)N);
            }
        }
        out[0] = ece;
    }
}

extern "C" void kernel_launch(void* const* d_in, const int* in_sizes, int n_in,
                              void* d_out, int out_size, void* d_ws, size_t ws_size,
                              hipStream_t stream) {
    const float* logits = (const float*)d_in[0];
    const int*   labels = (const int*)d_in[1];
    const int*   t_opt  = (const int*)d_in[2];
    float* out   = (float*)d_out;
    float* gbins = (float*)d_ws;

    const int N = in_sizes[1];               // 1,000,000 rows (C fixed at 100)

    hipMemsetAsync(gbins, 0, 3 * NBINS * sizeof(float), stream);

    const int nTiles = (N + TROWS - 1) / TROWS;
    const int blocks = nTiles < 768 ? nTiles : 768;   // 3 blocks/CU x 256 CU
    ece_main<<<blocks, BLOCK, 0, stream>>>(logits, labels, t_opt, gbins, N);
    ece_final<<<1, 64, 0, stream>>>(gbins, out, N);
}